// Round 13
// baseline (2068.615 us; speedup 1.0000x reference)
//
#include <hip/hip_runtime.h>
#include <hip/hip_bf16.h>

#define T_STEPS 512
#define BATCH   256
#define HID     100
#define GATES   400   // 4*H
#define BT      (BATCH * T_STEPS)

__device__ __forceinline__ float sigm_f(float x) {
    return 1.f / (1.f + __expf(-x));
}

__device__ __forceinline__ float tanh_f(float x) {
    float ax = fabsf(x);
    float t  = __expf(-2.f * ax);
    float r  = (1.f - t) / (1.f + t);
    return copysignf(r, x);
}

// fp32 -> bf16 (RNE) and back, as raw ushort bits
__device__ __forceinline__ unsigned short bf_hi(float f) {
    unsigned u = __float_as_uint(f);
    return (unsigned short)((u + 0x7FFFu + ((u >> 16) & 1u)) >> 16);
}
__device__ __forceinline__ float bf_f(unsigned short s) {
    return __uint_as_float(((unsigned)s) << 16);
}

typedef short v8s __attribute__((ext_vector_type(8)));   // 8 bf16 bit-patterns
typedef float v4f __attribute__((ext_vector_type(4)));

// ---------------------------------------------------------------------------
// xg GEMM v8 (MFMA bf16x3), unchanged from round 12 (absmax 0.0, fast):
// fp32 accuracy via split a=a_hi+a_lo (bf16): D += Ah*Bh + Ah*Bl + Al*Bh.
// BM=128, BN=128 (N=400 padded to 512), K-step 32, dbuf LDS, XOR swizzle,
// XCD swizzle. C/D layout per m89: col=lane&15, row=(lane>>4)*4+reg.
// ---------------------------------------------------------------------------
template <int K, int NK, bool GATHER>
__global__ __launch_bounds__(256) void xg_gemm(
    const float* __restrict__ A, const int* __restrict__ idx,
    const float* __restrict__ W, const float* __restrict__ b1,
    const float* __restrict__ b2, float* __restrict__ out)
{
    __shared__ unsigned short Ah[2][4096], Al[2][4096];   // 128 rows x 32 k
    __shared__ unsigned short Wh[2][4096], Wl[2][4096];
    __shared__ int idx_s[128];

    // bid = xcd + 8*(col_tile + 4*row_group)
    const int bid  = blockIdx.x;
    const int xcd  = bid & 7;
    const int rest = bid >> 3;
    const int ct   = rest & 3;
    const int rgrp = rest >> 2;
    const int row0 = (rgrp * 8 + xcd) * 128;
    const int col0 = ct * 128;

    const int tid  = threadIdx.x;
    const int lane = tid & 63;
    const int wave = tid >> 6;
    const int wm   = wave >> 1;      // wave row 0..1
    const int wn   = wave & 1;       // wave col 0..1
    const int lm   = lane & 15;
    const int lk   = lane >> 4;      // k-block 0..3

    if (GATHER) {
        if (tid < 128) idx_s[tid] = idx[row0 + tid];
        __syncthreads();
    }

    // staging assignment: thread -> (row sr, k-quads sq..sq+3)
    const int sr = tid >> 1;
    const int sq = (tid & 1) * 4;
    const float* arowp = GATHER ? (A + (size_t)idx_s[sr] * K)
                                : (A + (size_t)(row0 + sr) * K);
    const int    wrow  = col0 + sr;
    const bool   wval  = (wrow < GATES);
    const float* wrowp = W + (size_t)wrow * K;

    auto stage = [&](int ks, int buf) {
        const int k0 = ks * 32;
#pragma unroll
        for (int u = 0; u < 4; ++u) {
            int q  = sq + u;
            int kb = k0 + q * 4;
            float4 va = make_float4(0.f, 0.f, 0.f, 0.f);
            float4 vw = make_float4(0.f, 0.f, 0.f, 0.f);
            if (kb < K) {
                va = *(const float4*)(arowp + kb);
                if (wval) vw = *(const float4*)(wrowp + kb);
            }
            int bo = sr * 64 + q * 8;
            int so = bo ^ (((bo >> 6) & 7) << 4);
            unsigned short h0 = bf_hi(va.x), h1 = bf_hi(va.y),
                           h2 = bf_hi(va.z), h3 = bf_hi(va.w);
            *(ushort4*)((char*)Ah[buf] + so) = make_ushort4(h0, h1, h2, h3);
            *(ushort4*)((char*)Al[buf] + so) = make_ushort4(
                bf_hi(va.x - bf_f(h0)), bf_hi(va.y - bf_f(h1)),
                bf_hi(va.z - bf_f(h2)), bf_hi(va.w - bf_f(h3)));
            h0 = bf_hi(vw.x); h1 = bf_hi(vw.y);
            h2 = bf_hi(vw.z); h3 = bf_hi(vw.w);
            *(ushort4*)((char*)Wh[buf] + so) = make_ushort4(h0, h1, h2, h3);
            *(ushort4*)((char*)Wl[buf] + so) = make_ushort4(
                bf_hi(vw.x - bf_f(h0)), bf_hi(vw.y - bf_f(h1)),
                bf_hi(vw.z - bf_f(h2)), bf_hi(vw.w - bf_f(h3)));
        }
    };

    stage(0, 0);

    v4f acc[4][4];
#pragma unroll
    for (int fm = 0; fm < 4; ++fm)
#pragma unroll
        for (int fn = 0; fn < 4; ++fn)
            acc[fm][fn] = (v4f){0.f, 0.f, 0.f, 0.f};

#pragma unroll 1
    for (int ks = 0; ks < NK; ++ks) {
        __syncthreads();   // buf[ks&1] staged; reads of buf[(ks+1)&1] done
        if (ks + 1 < NK) stage(ks + 1, (ks + 1) & 1);

        const int cur = ks & 1;
        v8s ah[4], al[4], bh[4], bl[4];
#pragma unroll
        for (int f = 0; f < 4; ++f) {
            int ra = (wm * 64 + f * 16 + lm) * 64 + lk * 16;
            ra ^= ((ra >> 6) & 7) << 4;
            ah[f] = *(const v8s*)((const char*)Ah[cur] + ra);
            al[f] = *(const v8s*)((const char*)Al[cur] + ra);
            int rb = (wn * 64 + f * 16 + lm) * 64 + lk * 16;
            rb ^= ((rb >> 6) & 7) << 4;
            bh[f] = *(const v8s*)((const char*)Wh[cur] + rb);
            bl[f] = *(const v8s*)((const char*)Wl[cur] + rb);
        }
#pragma unroll
        for (int fm = 0; fm < 4; ++fm) {
#pragma unroll
            for (int fn = 0; fn < 4; ++fn) {
                acc[fm][fn] = __builtin_amdgcn_mfma_f32_16x16x32_bf16(
                    ah[fm], bh[fn], acc[fm][fn], 0, 0, 0);
                acc[fm][fn] = __builtin_amdgcn_mfma_f32_16x16x32_bf16(
                    ah[fm], bl[fn], acc[fm][fn], 0, 0, 0);
                acc[fm][fn] = __builtin_amdgcn_mfma_f32_16x16x32_bf16(
                    al[fm], bh[fn], acc[fm][fn], 0, 0, 0);
            }
        }
    }

    // epilogue: bias + guarded store. D: col=lane&15, row=(lane>>4)*4+reg.
#pragma unroll
    for (int fn = 0; fn < 4; ++fn) {
        int col = col0 + wn * 64 + fn * 16 + lm;
        if (col < GATES) {
            float bias = b1[col] + b2[col];
#pragma unroll
            for (int fm = 0; fm < 4; ++fm) {
                v4f d = acc[fm][fn];
                int rbase = row0 + wm * 64 + fm * 16 + lk * 4;
#pragma unroll
                for (int p = 0; p < 4; ++p)
                    out[(size_t)(rbase + p) * GATES + col] = d[p] + bias;
            }
        }
    }
}

// ---------------------------------------------------------------------------
// Recurrent scan v6b: identical structure to round 12, ONE change:
// __launch_bounds__(448, 2). Round-12 counters showed VGPR_Count=80 while
// w4[4][28] alone needs 112 -- the compiler's default occupancy heuristic
// refused to keep the weights register-resident and re-loaded them from
// L1/L2 EVERY STEP (~12 TB/s aggregate, the real 50%-VALU wall). min-2
// waves/EU caps VGPR at 256 > ~190 live set, and 7 waves/block needs
// exactly 2 waves/SIMD, so occupancy is unchanged.
// ---------------------------------------------------------------------------
template <bool WRITE_ALL>
__global__ __launch_bounds__(448, 2) void lstm_recur(
    const float* __restrict__ xg,    // [B, T, 400]
    const float* __restrict__ w_hh,  // [400, 100]
    const int*   __restrict__ lengths,
    float* __restrict__ hs)          // [B, T, 100]
{
    const int b   = blockIdx.x;
    const int tid = threadIdx.x;
    const bool active = (tid < 400);
    const int j    = tid >> 2;
    const int gt   = tid & 3;

    __shared__ float xg_s[32 * GATES];
    __shared__ float h_s[2][112];
    __shared__ float h_hist[32 * HID];

    float w4[4][28];
    if (active) {
#pragma unroll
        for (int g = 0; g < 4; ++g) {
            const float* wr = w_hh + (size_t)(g * HID + j) * HID + gt * 25;
#pragma unroll
            for (int i = 0; i < 28; ++i)
                w4[g][i] = (i < 25) ? wr[i] : 0.f;
        }
    }
    for (int i = tid; i < 224; i += 448) ((float*)h_s)[i] = 0.f;

    float c_reg = 0.f, h_reg = 0.f;
    const int len = lengths[b];
    const float* xgb = xg + (size_t)b * T_STEPS * GATES;
    float*       hsb = hs + (size_t)b * T_STEPS * HID;

    const bool is0 = (gt == 0), is1 = (gt == 1), is2 = (gt == 2);
    const int  hoff = gt * 28;
    const int  seg  = (j / 25) * 28 + (j % 25);
    const int  xcol = gt * HID + j;

    for (int t = 0; t < T_STEPS; ++t) {
        if ((t & 31) == 0) {
            if (WRITE_ALL && t > 0) {
                const float4* s = (const float4*)h_hist;
                float4*       d = (float4*)(hsb + (size_t)(t - 32) * HID);
                for (int i = tid; i < 800; i += 448) d[i] = s[i];
            }
            const float4* src = (const float4*)(xgb + (size_t)t * GATES);
            float4*       dst = (float4*)xg_s;
            for (int i = tid; i < 3200; i += 448) dst[i] = src[i];
            __syncthreads();
        }

        float s0 = 0.f, s1 = 0.f, s2 = 0.f, s3 = 0.f;
        if (active) {
            const float* hb = h_s[t & 1] + hoff;
#pragma unroll
            for (int i = 0; i < 28; i += 4) {
                float4 h4 = *(const float4*)(hb + i);
                s0 += w4[0][i] * h4.x + w4[0][i+1] * h4.y +
                      w4[0][i+2] * h4.z + w4[0][i+3] * h4.w;
                s1 += w4[1][i] * h4.x + w4[1][i+1] * h4.y +
                      w4[1][i+2] * h4.z + w4[1][i+3] * h4.w;
                s2 += w4[2][i] * h4.x + w4[2][i+1] * h4.y +
                      w4[2][i+2] * h4.z + w4[2][i+3] * h4.w;
                s3 += w4[3][i] * h4.x + w4[3][i+1] * h4.y +
                      w4[3][i+2] * h4.z + w4[3][i+3] * h4.w;
            }
        }
        s0 += __shfl_xor(s0, 1); s0 += __shfl_xor(s0, 2);
        s1 += __shfl_xor(s1, 1); s1 += __shfl_xor(s1, 2);
        s2 += __shfl_xor(s2, 1); s2 += __shfl_xor(s2, 2);
        s3 += __shfl_xor(s3, 1); s3 += __shfl_xor(s3, 2);

        float sg = is0 ? s0 : is1 ? s1 : is2 ? s2 : s3;
        float pre = 0.f;
        if (active)
            pre = sg + xg_s[(t & 31) * GATES + xcol];

        float p0 = is2 ? tanh_f(pre) : sigm_f(pre);
        float p1 = __shfl_xor(p0, 1);
        float p2 = __shfl_xor(p0, 2);
        float p3 = __shfl_xor(p1, 2);
        float iv = is0 ? p0 : is1 ? p1 : is2 ? p2 : p3;
        float fv = is0 ? p1 : is1 ? p0 : is2 ? p3 : p2;
        float gv = is0 ? p2 : is1 ? p3 : is2 ? p0 : p1;
        float ov = is0 ? p3 : is1 ? p2 : is2 ? p1 : p0;

        float c_new = fv * c_reg + iv * gv;
        float h_new = ov * tanh_f(c_new);
        bool  m     = (t < len);
        c_reg = m ? c_new : c_reg;
        h_reg = m ? h_new : h_reg;

        if (active && gt == 0) {
            h_s[(t & 1) ^ 1][seg] = h_reg;
            if (WRITE_ALL) h_hist[(t & 31) * HID + j] = h_reg;
        }
        __syncthreads();
    }

    if (WRITE_ALL) {
        const float4* s = (const float4*)h_hist;
        float4*       d = (float4*)(hsb + (size_t)(T_STEPS - 32) * HID);
        for (int i = tid; i < 800; i += 448) d[i] = s[i];
    } else {
        if (active && gt == 0)
            hsb[(size_t)(T_STEPS - 1) * HID + j] = h_reg;
    }
}

// ---------------------------------------------------------------------------
// Final linear head
// ---------------------------------------------------------------------------
__global__ __launch_bounds__(64) void fc_kernel(
    const float* __restrict__ hs, const float* __restrict__ w_fc,
    const float* __restrict__ b_fc, float* __restrict__ out)
{
    int tid = blockIdx.x * 64 + threadIdx.x;
    if (tid >= BATCH * 3) return;
    int b = tid / 3, o = tid % 3;
    const float* h = hs + ((size_t)b * T_STEPS + (T_STEPS - 1)) * HID;
    float acc = b_fc[o];
    for (int j = 0; j < HID; ++j) acc += h[j] * w_fc[o * HID + j];
    out[b * 3 + o] = acc;
}

extern "C" void kernel_launch(void* const* d_in, const int* in_sizes, int n_in,
                              void* d_out, int out_size, void* d_ws, size_t ws_size,
                              hipStream_t stream)
{
    const int*   x       = (const int*)  d_in[0];
    const int*   lengths = (const int*)  d_in[1];
    const float* emb     = (const float*)d_in[2];
    const float* w_ih0   = (const float*)d_in[3];
    const float* w_hh0   = (const float*)d_in[4];
    const float* b_ih0   = (const float*)d_in[5];
    const float* b_hh0   = (const float*)d_in[6];
    const float* w_ih1   = (const float*)d_in[7];
    const float* w_hh1   = (const float*)d_in[8];
    const float* b_ih1   = (const float*)d_in[9];
    const float* b_hh1   = (const float*)d_in[10];
    const float* w_ih2   = (const float*)d_in[11];
    const float* w_hh2   = (const float*)d_in[12];
    const float* b_ih2   = (const float*)d_in[13];
    const float* b_hh2   = (const float*)d_in[14];
    const float* w_fc    = (const float*)d_in[15];
    const float* b_fc    = (const float*)d_in[16];
    float* out = (float*)d_out;

    float* xg = (float*)d_ws;                  // [BT, 400]  ~210 MB
    float* hs = xg + (size_t)BT * GATES;       // [BT, 100]  ~52 MB

    const int nblk = (BT / 128) * 4;   // 4096, XCD-swizzled inside kernel

    // Layer 0: embedding gather fused into staging, K=300 (pad 320)
    xg_gemm<300, 10, true><<<nblk, 256, 0, stream>>>(emb, x, w_ih0, b_ih0, b_hh0, xg);
    lstm_recur<true><<<BATCH, 448, 0, stream>>>(xg, w_hh0, lengths, hs);

    // Layer 1: K=100 (pad 128)
    xg_gemm<100, 4, false><<<nblk, 256, 0, stream>>>(hs, nullptr, w_ih1, b_ih1, b_hh1, xg);
    lstm_recur<true><<<BATCH, 448, 0, stream>>>(xg, w_hh1, lengths, hs);

    // Layer 2
    xg_gemm<100, 4, false><<<nblk, 256, 0, stream>>>(hs, nullptr, w_ih2, b_ih2, b_hh2, xg);
    lstm_recur<false><<<BATCH, 448, 0, stream>>>(xg, w_hh2, lengths, hs);

    // Head
    fc_kernel<<<(BATCH * 3 + 63) / 64, 64, 0, stream>>>(hs, w_fc, b_fc, out);
}

// Round 14
// 2049.196 us; speedup vs baseline: 1.0095x; 1.0095x over previous
//
#include <hip/hip_runtime.h>
#include <hip/hip_bf16.h>

#define T_STEPS 512
#define BATCH   256
#define HID     100
#define GATES   400   // 4*H
#define BT      (BATCH * T_STEPS)

__device__ __forceinline__ float sigm_f(float x) {
    return 1.f / (1.f + __expf(-x));
}

__device__ __forceinline__ float tanh_f(float x) {
    float ax = fabsf(x);
    float t  = __expf(-2.f * ax);
    float r  = (1.f - t) / (1.f + t);
    return copysignf(r, x);
}

// fp32 -> bf16 (RNE) and back, as raw ushort bits
__device__ __forceinline__ unsigned short bf_hi(float f) {
    unsigned u = __float_as_uint(f);
    return (unsigned short)((u + 0x7FFFu + ((u >> 16) & 1u)) >> 16);
}
__device__ __forceinline__ float bf_f(unsigned short s) {
    return __uint_as_float(((unsigned)s) << 16);
}

typedef short v8s __attribute__((ext_vector_type(8)));   // 8 bf16 bit-patterns
typedef float v4f __attribute__((ext_vector_type(4)));

// ---------------------------------------------------------------------------
// xg GEMM v8 (MFMA bf16x3), unchanged from round 12 (absmax 0.0, fast):
// fp32 accuracy via split a=a_hi+a_lo (bf16): D += Ah*Bh + Ah*Bl + Al*Bh.
// BM=128, BN=128 (N=400 padded to 512), K-step 32, dbuf LDS, XOR swizzle,
// XCD swizzle. C/D layout per m89: col=lane&15, row=(lane>>4)*4+reg.
// ---------------------------------------------------------------------------
template <int K, int NK, bool GATHER>
__global__ __launch_bounds__(256) void xg_gemm(
    const float* __restrict__ A, const int* __restrict__ idx,
    const float* __restrict__ W, const float* __restrict__ b1,
    const float* __restrict__ b2, float* __restrict__ out)
{
    __shared__ unsigned short Ah[2][4096], Al[2][4096];   // 128 rows x 32 k
    __shared__ unsigned short Wh[2][4096], Wl[2][4096];
    __shared__ int idx_s[128];

    // bid = xcd + 8*(col_tile + 4*row_group)
    const int bid  = blockIdx.x;
    const int xcd  = bid & 7;
    const int rest = bid >> 3;
    const int ct   = rest & 3;
    const int rgrp = rest >> 2;
    const int row0 = (rgrp * 8 + xcd) * 128;
    const int col0 = ct * 128;

    const int tid  = threadIdx.x;
    const int lane = tid & 63;
    const int wave = tid >> 6;
    const int wm   = wave >> 1;      // wave row 0..1
    const int wn   = wave & 1;       // wave col 0..1
    const int lm   = lane & 15;
    const int lk   = lane >> 4;      // k-block 0..3

    if (GATHER) {
        if (tid < 128) idx_s[tid] = idx[row0 + tid];
        __syncthreads();
    }

    // staging assignment: thread -> (row sr, k-quads sq..sq+3)
    const int sr = tid >> 1;
    const int sq = (tid & 1) * 4;
    const float* arowp = GATHER ? (A + (size_t)idx_s[sr] * K)
                                : (A + (size_t)(row0 + sr) * K);
    const int    wrow  = col0 + sr;
    const bool   wval  = (wrow < GATES);
    const float* wrowp = W + (size_t)wrow * K;

    auto stage = [&](int ks, int buf) {
        const int k0 = ks * 32;
#pragma unroll
        for (int u = 0; u < 4; ++u) {
            int q  = sq + u;
            int kb = k0 + q * 4;
            float4 va = make_float4(0.f, 0.f, 0.f, 0.f);
            float4 vw = make_float4(0.f, 0.f, 0.f, 0.f);
            if (kb < K) {
                va = *(const float4*)(arowp + kb);
                if (wval) vw = *(const float4*)(wrowp + kb);
            }
            int bo = sr * 64 + q * 8;
            int so = bo ^ (((bo >> 6) & 7) << 4);
            unsigned short h0 = bf_hi(va.x), h1 = bf_hi(va.y),
                           h2 = bf_hi(va.z), h3 = bf_hi(va.w);
            *(ushort4*)((char*)Ah[buf] + so) = make_ushort4(h0, h1, h2, h3);
            *(ushort4*)((char*)Al[buf] + so) = make_ushort4(
                bf_hi(va.x - bf_f(h0)), bf_hi(va.y - bf_f(h1)),
                bf_hi(va.z - bf_f(h2)), bf_hi(va.w - bf_f(h3)));
            h0 = bf_hi(vw.x); h1 = bf_hi(vw.y);
            h2 = bf_hi(vw.z); h3 = bf_hi(vw.w);
            *(ushort4*)((char*)Wh[buf] + so) = make_ushort4(h0, h1, h2, h3);
            *(ushort4*)((char*)Wl[buf] + so) = make_ushort4(
                bf_hi(vw.x - bf_f(h0)), bf_hi(vw.y - bf_f(h1)),
                bf_hi(vw.z - bf_f(h2)), bf_hi(vw.w - bf_f(h3)));
        }
    };

    stage(0, 0);

    v4f acc[4][4];
#pragma unroll
    for (int fm = 0; fm < 4; ++fm)
#pragma unroll
        for (int fn = 0; fn < 4; ++fn)
            acc[fm][fn] = (v4f){0.f, 0.f, 0.f, 0.f};

#pragma unroll 1
    for (int ks = 0; ks < NK; ++ks) {
        __syncthreads();   // buf[ks&1] staged; reads of buf[(ks+1)&1] done
        if (ks + 1 < NK) stage(ks + 1, (ks + 1) & 1);

        const int cur = ks & 1;
        v8s ah[4], al[4], bh[4], bl[4];
#pragma unroll
        for (int f = 0; f < 4; ++f) {
            int ra = (wm * 64 + f * 16 + lm) * 64 + lk * 16;
            ra ^= ((ra >> 6) & 7) << 4;
            ah[f] = *(const v8s*)((const char*)Ah[cur] + ra);
            al[f] = *(const v8s*)((const char*)Al[cur] + ra);
            int rb = (wn * 64 + f * 16 + lm) * 64 + lk * 16;
            rb ^= ((rb >> 6) & 7) << 4;
            bh[f] = *(const v8s*)((const char*)Wh[cur] + rb);
            bl[f] = *(const v8s*)((const char*)Wl[cur] + rb);
        }
#pragma unroll
        for (int fm = 0; fm < 4; ++fm) {
#pragma unroll
            for (int fn = 0; fn < 4; ++fn) {
                acc[fm][fn] = __builtin_amdgcn_mfma_f32_16x16x32_bf16(
                    ah[fm], bh[fn], acc[fm][fn], 0, 0, 0);
                acc[fm][fn] = __builtin_amdgcn_mfma_f32_16x16x32_bf16(
                    ah[fm], bl[fn], acc[fm][fn], 0, 0, 0);
                acc[fm][fn] = __builtin_amdgcn_mfma_f32_16x16x32_bf16(
                    al[fm], bh[fn], acc[fm][fn], 0, 0, 0);
            }
        }
    }

    // epilogue: bias + guarded store. D: col=lane&15, row=(lane>>4)*4+reg.
#pragma unroll
    for (int fn = 0; fn < 4; ++fn) {
        int col = col0 + wn * 64 + fn * 16 + lm;
        if (col < GATES) {
            float bias = b1[col] + b2[col];
#pragma unroll
            for (int fm = 0; fm < 4; ++fm) {
                v4f d = acc[fm][fn];
                int rbase = row0 + wm * 64 + fm * 16 + lk * 4;
#pragma unroll
                for (int p = 0; p < 4; ++p)
                    out[(size_t)(rbase + p) * GATES + col] = d[p] + bias;
            }
        }
    }
}

// ---------------------------------------------------------------------------
// Recurrent scan v6c: round-12 structure, two promotion fixes:
//  (1) weights flattened to w4[112] with all-constant indices (SROA-friendly)
//  (2) asm keep-alive on each element after load -- the empty asm REDEFINES
//      the value, so the compiler cannot re-materialize it by re-loading
//      from w_hh inside the t-loop (round 12/13: VGPR=80 < the 112-float
//      weight set; it was re-fetching weights from L2 every step, ~2560
//      cyc/step latency chain).
// __launch_bounds__(448,2) gives the 256-VGPR budget the live set needs.
// ---------------------------------------------------------------------------
template <bool WRITE_ALL>
__global__ __launch_bounds__(448, 2) void lstm_recur(
    const float* __restrict__ xg,    // [B, T, 400]
    const float* __restrict__ w_hh,  // [400, 100]
    const int*   __restrict__ lengths,
    float* __restrict__ hs)          // [B, T, 100]
{
    const int b   = blockIdx.x;
    const int tid = threadIdx.x;
    const bool active = (tid < 400);
    const int j    = tid >> 2;
    const int gt   = tid & 3;

    __shared__ float xg_s[32 * GATES];
    __shared__ float h_s[2][112];
    __shared__ float h_hist[32 * HID];

    float w4[112];
    if (active) {
#pragma unroll
        for (int g = 0; g < 4; ++g) {
            const float* wr = w_hh + (size_t)(g * HID + j) * HID + gt * 25;
#pragma unroll
            for (int i = 0; i < 28; ++i)
                w4[g * 28 + i] = (i < 25) ? wr[i] : 0.f;
        }
#pragma unroll
        for (int i = 0; i < 112; ++i)
            asm volatile("" : "+v"(w4[i]));   // force register residency
    }
    for (int i = tid; i < 224; i += 448) ((float*)h_s)[i] = 0.f;

    float c_reg = 0.f, h_reg = 0.f;
    const int len = lengths[b];
    const float* xgb = xg + (size_t)b * T_STEPS * GATES;
    float*       hsb = hs + (size_t)b * T_STEPS * HID;

    const bool is0 = (gt == 0), is1 = (gt == 1), is2 = (gt == 2);
    const int  hoff = gt * 28;
    const int  seg  = (j / 25) * 28 + (j % 25);
    const int  xcol = gt * HID + j;

    for (int t = 0; t < T_STEPS; ++t) {
        if ((t & 31) == 0) {
            if (WRITE_ALL && t > 0) {
                const float4* s = (const float4*)h_hist;
                float4*       d = (float4*)(hsb + (size_t)(t - 32) * HID);
                for (int i = tid; i < 800; i += 448) d[i] = s[i];
            }
            const float4* src = (const float4*)(xgb + (size_t)t * GATES);
            float4*       dst = (float4*)xg_s;
            for (int i = tid; i < 3200; i += 448) dst[i] = src[i];
            __syncthreads();
        }

        float s0 = 0.f, s1 = 0.f, s2 = 0.f, s3 = 0.f;
        if (active) {
            const float* hb = h_s[t & 1] + hoff;
#pragma unroll
            for (int i = 0; i < 28; i += 4) {
                float4 h4 = *(const float4*)(hb + i);
                s0 += w4[0 * 28 + i]     * h4.x + w4[0 * 28 + i + 1] * h4.y +
                      w4[0 * 28 + i + 2] * h4.z + w4[0 * 28 + i + 3] * h4.w;
                s1 += w4[1 * 28 + i]     * h4.x + w4[1 * 28 + i + 1] * h4.y +
                      w4[1 * 28 + i + 2] * h4.z + w4[1 * 28 + i + 3] * h4.w;
                s2 += w4[2 * 28 + i]     * h4.x + w4[2 * 28 + i + 1] * h4.y +
                      w4[2 * 28 + i + 2] * h4.z + w4[2 * 28 + i + 3] * h4.w;
                s3 += w4[3 * 28 + i]     * h4.x + w4[3 * 28 + i + 1] * h4.y +
                      w4[3 * 28 + i + 2] * h4.z + w4[3 * 28 + i + 3] * h4.w;
            }
        }
        s0 += __shfl_xor(s0, 1); s0 += __shfl_xor(s0, 2);
        s1 += __shfl_xor(s1, 1); s1 += __shfl_xor(s1, 2);
        s2 += __shfl_xor(s2, 1); s2 += __shfl_xor(s2, 2);
        s3 += __shfl_xor(s3, 1); s3 += __shfl_xor(s3, 2);

        float sg = is0 ? s0 : is1 ? s1 : is2 ? s2 : s3;
        float pre = 0.f;
        if (active)
            pre = sg + xg_s[(t & 31) * GATES + xcol];

        float p0 = is2 ? tanh_f(pre) : sigm_f(pre);
        float p1 = __shfl_xor(p0, 1);
        float p2 = __shfl_xor(p0, 2);
        float p3 = __shfl_xor(p1, 2);
        float iv = is0 ? p0 : is1 ? p1 : is2 ? p2 : p3;
        float fv = is0 ? p1 : is1 ? p0 : is2 ? p3 : p2;
        float gv = is0 ? p2 : is1 ? p3 : is2 ? p0 : p1;
        float ov = is0 ? p3 : is1 ? p2 : is2 ? p1 : p0;

        float c_new = fv * c_reg + iv * gv;
        float h_new = ov * tanh_f(c_new);
        bool  m     = (t < len);
        c_reg = m ? c_new : c_reg;
        h_reg = m ? h_new : h_reg;

        if (active && gt == 0) {
            h_s[(t & 1) ^ 1][seg] = h_reg;
            if (WRITE_ALL) h_hist[(t & 31) * HID + j] = h_reg;
        }
        __syncthreads();
    }

    if (WRITE_ALL) {
        const float4* s = (const float4*)h_hist;
        float4*       d = (float4*)(hsb + (size_t)(T_STEPS - 32) * HID);
        for (int i = tid; i < 800; i += 448) d[i] = s[i];
    } else {
        if (active && gt == 0)
            hsb[(size_t)(T_STEPS - 1) * HID + j] = h_reg;
    }
}

// ---------------------------------------------------------------------------
// Final linear head
// ---------------------------------------------------------------------------
__global__ __launch_bounds__(64) void fc_kernel(
    const float* __restrict__ hs, const float* __restrict__ w_fc,
    const float* __restrict__ b_fc, float* __restrict__ out)
{
    int tid = blockIdx.x * 64 + threadIdx.x;
    if (tid >= BATCH * 3) return;
    int b = tid / 3, o = tid % 3;
    const float* h = hs + ((size_t)b * T_STEPS + (T_STEPS - 1)) * HID;
    float acc = b_fc[o];
    for (int j = 0; j < HID; ++j) acc += h[j] * w_fc[o * HID + j];
    out[b * 3 + o] = acc;
}

extern "C" void kernel_launch(void* const* d_in, const int* in_sizes, int n_in,
                              void* d_out, int out_size, void* d_ws, size_t ws_size,
                              hipStream_t stream)
{
    const int*   x       = (const int*)  d_in[0];
    const int*   lengths = (const int*)  d_in[1];
    const float* emb     = (const float*)d_in[2];
    const float* w_ih0   = (const float*)d_in[3];
    const float* w_hh0   = (const float*)d_in[4];
    const float* b_ih0   = (const float*)d_in[5];
    const float* b_hh0   = (const float*)d_in[6];
    const float* w_ih1   = (const float*)d_in[7];
    const float* w_hh1   = (const float*)d_in[8];
    const float* b_ih1   = (const float*)d_in[9];
    const float* b_hh1   = (const float*)d_in[10];
    const float* w_ih2   = (const float*)d_in[11];
    const float* w_hh2   = (const float*)d_in[12];
    const float* b_ih2   = (const float*)d_in[13];
    const float* b_hh2   = (const float*)d_in[14];
    const float* w_fc    = (const float*)d_in[15];
    const float* b_fc    = (const float*)d_in[16];
    float* out = (float*)d_out;

    float* xg = (float*)d_ws;                  // [BT, 400]  ~210 MB
    float* hs = xg + (size_t)BT * GATES;       // [BT, 100]  ~52 MB

    const int nblk = (BT / 128) * 4;   // 4096, XCD-swizzled inside kernel

    // Layer 0: embedding gather fused into staging, K=300 (pad 320)
    xg_gemm<300, 10, true><<<nblk, 256, 0, stream>>>(emb, x, w_ih0, b_ih0, b_hh0, xg);
    lstm_recur<true><<<BATCH, 448, 0, stream>>>(xg, w_hh0, lengths, hs);

    // Layer 1: K=100 (pad 128)
    xg_gemm<100, 4, false><<<nblk, 256, 0, stream>>>(hs, nullptr, w_ih1, b_ih1, b_hh1, xg);
    lstm_recur<true><<<BATCH, 448, 0, stream>>>(xg, w_hh1, lengths, hs);

    // Layer 2
    xg_gemm<100, 4, false><<<nblk, 256, 0, stream>>>(hs, nullptr, w_ih2, b_ih2, b_hh2, xg);
    lstm_recur<false><<<BATCH, 448, 0, stream>>>(xg, w_hh2, lengths, hs);

    // Head
    fc_kernel<<<(BATCH * 3 + 63) / 64, 64, 0, stream>>>(hs, w_fc, b_fc, out);
}

// Round 15
// 2046.556 us; speedup vs baseline: 1.0108x; 1.0013x over previous
//
#include <hip/hip_runtime.h>
#include <hip/hip_bf16.h>

#define T_STEPS 512
#define BATCH   256
#define HID     100
#define GATES   400   // 4*H
#define BT      (BATCH * T_STEPS)

__device__ __forceinline__ float sigm_f(float x) {
    return 1.f / (1.f + __expf(-x));
}

__device__ __forceinline__ float tanh_f(float x) {
    float ax = fabsf(x);
    float t  = __expf(-2.f * ax);
    float r  = (1.f - t) / (1.f + t);
    return copysignf(r, x);
}

// fp32 -> bf16 (RNE) and back, as raw ushort bits
__device__ __forceinline__ unsigned short bf_hi(float f) {
    unsigned u = __float_as_uint(f);
    return (unsigned short)((u + 0x7FFFu + ((u >> 16) & 1u)) >> 16);
}
__device__ __forceinline__ float bf_f(unsigned short s) {
    return __uint_as_float(((unsigned)s) << 16);
}

typedef short v8s __attribute__((ext_vector_type(8)));   // 8 bf16 bit-patterns
typedef float v4f __attribute__((ext_vector_type(4)));

// ---------------------------------------------------------------------------
// xg GEMM v8 (MFMA bf16x3), unchanged since round 12 (absmax 0.0):
// D += Ah*Bh + Ah*Bl + Al*Bh. BM=128, BN=128 (400 padded to 512), K-step 32,
// dbuf LDS, XOR swizzle, XCD swizzle. C/D: col=lane&15, row=(lane>>4)*4+reg.
// ---------------------------------------------------------------------------
template <int K, int NK, bool GATHER>
__global__ __launch_bounds__(256) void xg_gemm(
    const float* __restrict__ A, const int* __restrict__ idx,
    const float* __restrict__ W, const float* __restrict__ b1,
    const float* __restrict__ b2, float* __restrict__ out)
{
    __shared__ unsigned short Ah[2][4096], Al[2][4096];   // 128 rows x 32 k
    __shared__ unsigned short Wh[2][4096], Wl[2][4096];
    __shared__ int idx_s[128];

    const int bid  = blockIdx.x;
    const int xcd  = bid & 7;
    const int rest = bid >> 3;
    const int ct   = rest & 3;
    const int rgrp = rest >> 2;
    const int row0 = (rgrp * 8 + xcd) * 128;
    const int col0 = ct * 128;

    const int tid  = threadIdx.x;
    const int lane = tid & 63;
    const int wave = tid >> 6;
    const int wm   = wave >> 1;
    const int wn   = wave & 1;
    const int lm   = lane & 15;
    const int lk   = lane >> 4;

    if (GATHER) {
        if (tid < 128) idx_s[tid] = idx[row0 + tid];
        __syncthreads();
    }

    const int sr = tid >> 1;
    const int sq = (tid & 1) * 4;
    const float* arowp = GATHER ? (A + (size_t)idx_s[sr] * K)
                                : (A + (size_t)(row0 + sr) * K);
    const int    wrow  = col0 + sr;
    const bool   wval  = (wrow < GATES);
    const float* wrowp = W + (size_t)wrow * K;

    auto stage = [&](int ks, int buf) {
        const int k0 = ks * 32;
#pragma unroll
        for (int u = 0; u < 4; ++u) {
            int q  = sq + u;
            int kb = k0 + q * 4;
            float4 va = make_float4(0.f, 0.f, 0.f, 0.f);
            float4 vw = make_float4(0.f, 0.f, 0.f, 0.f);
            if (kb < K) {
                va = *(const float4*)(arowp + kb);
                if (wval) vw = *(const float4*)(wrowp + kb);
            }
            int bo = sr * 64 + q * 8;
            int so = bo ^ (((bo >> 6) & 7) << 4);
            unsigned short h0 = bf_hi(va.x), h1 = bf_hi(va.y),
                           h2 = bf_hi(va.z), h3 = bf_hi(va.w);
            *(ushort4*)((char*)Ah[buf] + so) = make_ushort4(h0, h1, h2, h3);
            *(ushort4*)((char*)Al[buf] + so) = make_ushort4(
                bf_hi(va.x - bf_f(h0)), bf_hi(va.y - bf_f(h1)),
                bf_hi(va.z - bf_f(h2)), bf_hi(va.w - bf_f(h3)));
            h0 = bf_hi(vw.x); h1 = bf_hi(vw.y);
            h2 = bf_hi(vw.z); h3 = bf_hi(vw.w);
            *(ushort4*)((char*)Wh[buf] + so) = make_ushort4(h0, h1, h2, h3);
            *(ushort4*)((char*)Wl[buf] + so) = make_ushort4(
                bf_hi(vw.x - bf_f(h0)), bf_hi(vw.y - bf_f(h1)),
                bf_hi(vw.z - bf_f(h2)), bf_hi(vw.w - bf_f(h3)));
        }
    };

    stage(0, 0);

    v4f acc[4][4];
#pragma unroll
    for (int fm = 0; fm < 4; ++fm)
#pragma unroll
        for (int fn = 0; fn < 4; ++fn)
            acc[fm][fn] = (v4f){0.f, 0.f, 0.f, 0.f};

#pragma unroll 1
    for (int ks = 0; ks < NK; ++ks) {
        __syncthreads();
        if (ks + 1 < NK) stage(ks + 1, (ks + 1) & 1);

        const int cur = ks & 1;
        v8s ah[4], al[4], bh[4], bl[4];
#pragma unroll
        for (int f = 0; f < 4; ++f) {
            int ra = (wm * 64 + f * 16 + lm) * 64 + lk * 16;
            ra ^= ((ra >> 6) & 7) << 4;
            ah[f] = *(const v8s*)((const char*)Ah[cur] + ra);
            al[f] = *(const v8s*)((const char*)Al[cur] + ra);
            int rb = (wn * 64 + f * 16 + lm) * 64 + lk * 16;
            rb ^= ((rb >> 6) & 7) << 4;
            bh[f] = *(const v8s*)((const char*)Wh[cur] + rb);
            bl[f] = *(const v8s*)((const char*)Wl[cur] + rb);
        }
#pragma unroll
        for (int fm = 0; fm < 4; ++fm) {
#pragma unroll
            for (int fn = 0; fn < 4; ++fn) {
                acc[fm][fn] = __builtin_amdgcn_mfma_f32_16x16x32_bf16(
                    ah[fm], bh[fn], acc[fm][fn], 0, 0, 0);
                acc[fm][fn] = __builtin_amdgcn_mfma_f32_16x16x32_bf16(
                    ah[fm], bl[fn], acc[fm][fn], 0, 0, 0);
                acc[fm][fn] = __builtin_amdgcn_mfma_f32_16x16x32_bf16(
                    al[fm], bh[fn], acc[fm][fn], 0, 0, 0);
            }
        }
    }

#pragma unroll
    for (int fn = 0; fn < 4; ++fn) {
        int col = col0 + wn * 64 + fn * 16 + lm;
        if (col < GATES) {
            float bias = b1[col] + b2[col];
#pragma unroll
            for (int fm = 0; fm < 4; ++fm) {
                v4f d = acc[fm][fn];
                int rbase = row0 + wm * 64 + fm * 16 + lk * 4;
#pragma unroll
                for (int p = 0; p < 4; ++p)
                    out[(size_t)(rbase + p) * GATES + col] = d[p] + bias;
            }
        }
    }
}

// ---------------------------------------------------------------------------
// Recurrent scan v6d: force weight promotion.
//  - amdgpu_waves_per_eu(2,2): max=2 waves/EU removes the allocator's
//    occupancy incentive to spill (rounds 12-14: VGPR 80-88 < the 112-float
//    weight set; every variant paid ~26 GB of scratch reloads / L2 ~= the
//    measured ~545 us wall).
//  - weight loads UNCONDITIONAL (clamped j) -- conditionally-defined values
//    across a barrier loop trigger remat-into-loop.
// ---------------------------------------------------------------------------
template <bool WRITE_ALL>
__global__ void
__attribute__((amdgpu_flat_work_group_size(448, 448), amdgpu_waves_per_eu(2, 2)))
lstm_recur(
    const float* __restrict__ xg,    // [B, T, 400]
    const float* __restrict__ w_hh,  // [400, 100]
    const int*   __restrict__ lengths,
    float* __restrict__ hs)          // [B, T, 100]
{
    const int b   = blockIdx.x;
    const int tid = threadIdx.x;
    const bool active = (tid < 400);
    const int j    = tid >> 2;
    const int jc   = (j < HID) ? j : (HID - 1);   // clamp: loads unconditional
    const int gt   = tid & 3;

    __shared__ float xg_s[32 * GATES];
    __shared__ float h_s[2][112];
    __shared__ float h_hist[32 * HID];

    float w4[112];
#pragma unroll
    for (int g = 0; g < 4; ++g) {
        const float* wr = w_hh + (size_t)(g * HID + jc) * HID + gt * 25;
#pragma unroll
        for (int i = 0; i < 28; ++i)
            w4[g * 28 + i] = (i < 25) ? wr[i] : 0.f;
    }
#pragma unroll
    for (int i = 0; i < 112; ++i)
        asm volatile("" : "+v"(w4[i]));   // keep register-resident

    for (int i = tid; i < 224; i += 448) ((float*)h_s)[i] = 0.f;

    float c_reg = 0.f, h_reg = 0.f;
    const int len = lengths[b];
    const float* xgb = xg + (size_t)b * T_STEPS * GATES;
    float*       hsb = hs + (size_t)b * T_STEPS * HID;

    const bool is0 = (gt == 0), is1 = (gt == 1), is2 = (gt == 2);
    const int  hoff = gt * 28;
    const int  seg  = (jc / 25) * 28 + (jc % 25);
    const int  xcol = gt * HID + jc;

    for (int t = 0; t < T_STEPS; ++t) {
        if ((t & 31) == 0) {
            if (WRITE_ALL && t > 0) {
                const float4* s = (const float4*)h_hist;
                float4*       d = (float4*)(hsb + (size_t)(t - 32) * HID);
                for (int i = tid; i < 800; i += 448) d[i] = s[i];
            }
            const float4* src = (const float4*)(xgb + (size_t)t * GATES);
            float4*       dst = (float4*)xg_s;
            for (int i = tid; i < 3200; i += 448) dst[i] = src[i];
            __syncthreads();
        }

        float s0 = 0.f, s1 = 0.f, s2 = 0.f, s3 = 0.f;
        {
            const float* hb = h_s[t & 1] + hoff;
#pragma unroll
            for (int i = 0; i < 28; i += 4) {
                float4 h4 = *(const float4*)(hb + i);
                s0 += w4[0 * 28 + i]     * h4.x + w4[0 * 28 + i + 1] * h4.y +
                      w4[0 * 28 + i + 2] * h4.z + w4[0 * 28 + i + 3] * h4.w;
                s1 += w4[1 * 28 + i]     * h4.x + w4[1 * 28 + i + 1] * h4.y +
                      w4[1 * 28 + i + 2] * h4.z + w4[1 * 28 + i + 3] * h4.w;
                s2 += w4[2 * 28 + i]     * h4.x + w4[2 * 28 + i + 1] * h4.y +
                      w4[2 * 28 + i + 2] * h4.z + w4[2 * 28 + i + 3] * h4.w;
                s3 += w4[3 * 28 + i]     * h4.x + w4[3 * 28 + i + 1] * h4.y +
                      w4[3 * 28 + i + 2] * h4.z + w4[3 * 28 + i + 3] * h4.w;
            }
        }
        s0 += __shfl_xor(s0, 1); s0 += __shfl_xor(s0, 2);
        s1 += __shfl_xor(s1, 1); s1 += __shfl_xor(s1, 2);
        s2 += __shfl_xor(s2, 1); s2 += __shfl_xor(s2, 2);
        s3 += __shfl_xor(s3, 1); s3 += __shfl_xor(s3, 2);

        float sg  = is0 ? s0 : is1 ? s1 : is2 ? s2 : s3;
        float pre = sg + xg_s[(t & 31) * GATES + xcol];

        float p0 = is2 ? tanh_f(pre) : sigm_f(pre);
        float p1 = __shfl_xor(p0, 1);
        float p2 = __shfl_xor(p0, 2);
        float p3 = __shfl_xor(p1, 2);
        float iv = is0 ? p0 : is1 ? p1 : is2 ? p2 : p3;
        float fv = is0 ? p1 : is1 ? p0 : is2 ? p3 : p2;
        float gv = is0 ? p2 : is1 ? p3 : is2 ? p0 : p1;
        float ov = is0 ? p3 : is1 ? p2 : is2 ? p1 : p0;

        float c_new = fv * c_reg + iv * gv;
        float h_new = ov * tanh_f(c_new);
        bool  m     = (t < len);
        c_reg = m ? c_new : c_reg;
        h_reg = m ? h_new : h_reg;

        if (active && gt == 0) {
            h_s[(t & 1) ^ 1][seg] = h_reg;
            if (WRITE_ALL) h_hist[(t & 31) * HID + j] = h_reg;
        }
        __syncthreads();
    }

    if (WRITE_ALL) {
        const float4* s = (const float4*)h_hist;
        float4*       d = (float4*)(hsb + (size_t)(T_STEPS - 32) * HID);
        for (int i = tid; i < 800; i += 448) d[i] = s[i];
    } else {
        if (active && gt == 0)
            hsb[(size_t)(T_STEPS - 1) * HID + j] = h_reg;
    }
}

// ---------------------------------------------------------------------------
// Final linear head
// ---------------------------------------------------------------------------
__global__ __launch_bounds__(64) void fc_kernel(
    const float* __restrict__ hs, const float* __restrict__ w_fc,
    const float* __restrict__ b_fc, float* __restrict__ out)
{
    int tid = blockIdx.x * 64 + threadIdx.x;
    if (tid >= BATCH * 3) return;
    int b = tid / 3, o = tid % 3;
    const float* h = hs + ((size_t)b * T_STEPS + (T_STEPS - 1)) * HID;
    float acc = b_fc[o];
    for (int j = 0; j < HID; ++j) acc += h[j] * w_fc[o * HID + j];
    out[b * 3 + o] = acc;
}

extern "C" void kernel_launch(void* const* d_in, const int* in_sizes, int n_in,
                              void* d_out, int out_size, void* d_ws, size_t ws_size,
                              hipStream_t stream)
{
    const int*   x       = (const int*)  d_in[0];
    const int*   lengths = (const int*)  d_in[1];
    const float* emb     = (const float*)d_in[2];
    const float* w_ih0   = (const float*)d_in[3];
    const float* w_hh0   = (const float*)d_in[4];
    const float* b_ih0   = (const float*)d_in[5];
    const float* b_hh0   = (const float*)d_in[6];
    const float* w_ih1   = (const float*)d_in[7];
    const float* w_hh1   = (const float*)d_in[8];
    const float* b_ih1   = (const float*)d_in[9];
    const float* b_hh1   = (const float*)d_in[10];
    const float* w_ih2   = (const float*)d_in[11];
    const float* w_hh2   = (const float*)d_in[12];
    const float* b_ih2   = (const float*)d_in[13];
    const float* b_hh2   = (const float*)d_in[14];
    const float* w_fc    = (const float*)d_in[15];
    const float* b_fc    = (const float*)d_in[16];
    float* out = (float*)d_out;

    float* xg = (float*)d_ws;                  // [BT, 400]  ~210 MB
    float* hs = xg + (size_t)BT * GATES;       // [BT, 100]  ~52 MB

    const int nblk = (BT / 128) * 4;   // 4096, XCD-swizzled inside kernel

    // Layer 0: embedding gather fused into staging, K=300 (pad 320)
    xg_gemm<300, 10, true><<<nblk, 256, 0, stream>>>(emb, x, w_ih0, b_ih0, b_hh0, xg);
    lstm_recur<true><<<BATCH, 448, 0, stream>>>(xg, w_hh0, lengths, hs);

    // Layer 1: K=100 (pad 128)
    xg_gemm<100, 4, false><<<nblk, 256, 0, stream>>>(hs, nullptr, w_ih1, b_ih1, b_hh1, xg);
    lstm_recur<true><<<BATCH, 448, 0, stream>>>(xg, w_hh1, lengths, hs);

    // Layer 2
    xg_gemm<100, 4, false><<<nblk, 256, 0, stream>>>(hs, nullptr, w_ih2, b_ih2, b_hh2, xg);
    lstm_recur<false><<<BATCH, 448, 0, stream>>>(xg, w_hh2, lengths, hs);

    // Head
    fc_kernel<<<(BATCH * 3 + 63) / 64, 64, 0, stream>>>(hs, w_fc, b_fc, out);
}

// Round 16
// 1907.371 us; speedup vs baseline: 1.0845x; 1.0730x over previous
//
#include <hip/hip_runtime.h>
#include <hip/hip_bf16.h>

#define T_STEPS 512
#define BATCH   256
#define HID     100
#define GATES   400   // 4*H
#define BT      (BATCH * T_STEPS)

__device__ __forceinline__ float sigm_f(float x) {
    return 1.f / (1.f + __expf(-x));
}

__device__ __forceinline__ float tanh_f(float x) {
    float ax = fabsf(x);
    float t  = __expf(-2.f * ax);
    float r  = (1.f - t) / (1.f + t);
    return copysignf(r, x);
}

// fp32 -> bf16 (RNE) and back, as raw ushort bits
__device__ __forceinline__ unsigned short bf_hi(float f) {
    unsigned u = __float_as_uint(f);
    return (unsigned short)((u + 0x7FFFu + ((u >> 16) & 1u)) >> 16);
}
__device__ __forceinline__ float bf_f(unsigned short s) {
    return __uint_as_float(((unsigned)s) << 16);
}

typedef short v8s __attribute__((ext_vector_type(8)));   // 8 bf16 bit-patterns
typedef float v4f __attribute__((ext_vector_type(4)));

// ---------------------------------------------------------------------------
// xg GEMM v8 (MFMA bf16x3), unchanged since round 12 (absmax 0.0):
// D += Ah*Bh + Ah*Bl + Al*Bh. BM=128, BN=128 (400 padded to 512), K-step 32,
// dbuf LDS, XOR swizzle, XCD swizzle. C/D: col=lane&15, row=(lane>>4)*4+reg.
// ---------------------------------------------------------------------------
template <int K, int NK, bool GATHER>
__global__ __launch_bounds__(256) void xg_gemm(
    const float* __restrict__ A, const int* __restrict__ idx,
    const float* __restrict__ W, const float* __restrict__ b1,
    const float* __restrict__ b2, float* __restrict__ out)
{
    __shared__ unsigned short Ah[2][4096], Al[2][4096];   // 128 rows x 32 k
    __shared__ unsigned short Wh[2][4096], Wl[2][4096];
    __shared__ int idx_s[128];

    const int bid  = blockIdx.x;
    const int xcd  = bid & 7;
    const int rest = bid >> 3;
    const int ct   = rest & 3;
    const int rgrp = rest >> 2;
    const int row0 = (rgrp * 8 + xcd) * 128;
    const int col0 = ct * 128;

    const int tid  = threadIdx.x;
    const int lane = tid & 63;
    const int wave = tid >> 6;
    const int wm   = wave >> 1;
    const int wn   = wave & 1;
    const int lm   = lane & 15;
    const int lk   = lane >> 4;

    if (GATHER) {
        if (tid < 128) idx_s[tid] = idx[row0 + tid];
        __syncthreads();
    }

    const int sr = tid >> 1;
    const int sq = (tid & 1) * 4;
    const float* arowp = GATHER ? (A + (size_t)idx_s[sr] * K)
                                : (A + (size_t)(row0 + sr) * K);
    const int    wrow  = col0 + sr;
    const bool   wval  = (wrow < GATES);
    const float* wrowp = W + (size_t)wrow * K;

    auto stage = [&](int ks, int buf) {
        const int k0 = ks * 32;
#pragma unroll
        for (int u = 0; u < 4; ++u) {
            int q  = sq + u;
            int kb = k0 + q * 4;
            float4 va = make_float4(0.f, 0.f, 0.f, 0.f);
            float4 vw = make_float4(0.f, 0.f, 0.f, 0.f);
            if (kb < K) {
                va = *(const float4*)(arowp + kb);
                if (wval) vw = *(const float4*)(wrowp + kb);
            }
            int bo = sr * 64 + q * 8;
            int so = bo ^ (((bo >> 6) & 7) << 4);
            unsigned short h0 = bf_hi(va.x), h1 = bf_hi(va.y),
                           h2 = bf_hi(va.z), h3 = bf_hi(va.w);
            *(ushort4*)((char*)Ah[buf] + so) = make_ushort4(h0, h1, h2, h3);
            *(ushort4*)((char*)Al[buf] + so) = make_ushort4(
                bf_hi(va.x - bf_f(h0)), bf_hi(va.y - bf_f(h1)),
                bf_hi(va.z - bf_f(h2)), bf_hi(va.w - bf_f(h3)));
            h0 = bf_hi(vw.x); h1 = bf_hi(vw.y);
            h2 = bf_hi(vw.z); h3 = bf_hi(vw.w);
            *(ushort4*)((char*)Wh[buf] + so) = make_ushort4(h0, h1, h2, h3);
            *(ushort4*)((char*)Wl[buf] + so) = make_ushort4(
                bf_hi(vw.x - bf_f(h0)), bf_hi(vw.y - bf_f(h1)),
                bf_hi(vw.z - bf_f(h2)), bf_hi(vw.w - bf_f(h3)));
        }
    };

    stage(0, 0);

    v4f acc[4][4];
#pragma unroll
    for (int fm = 0; fm < 4; ++fm)
#pragma unroll
        for (int fn = 0; fn < 4; ++fn)
            acc[fm][fn] = (v4f){0.f, 0.f, 0.f, 0.f};

#pragma unroll 1
    for (int ks = 0; ks < NK; ++ks) {
        __syncthreads();
        if (ks + 1 < NK) stage(ks + 1, (ks + 1) & 1);

        const int cur = ks & 1;
        v8s ah[4], al[4], bh[4], bl[4];
#pragma unroll
        for (int f = 0; f < 4; ++f) {
            int ra = (wm * 64 + f * 16 + lm) * 64 + lk * 16;
            ra ^= ((ra >> 6) & 7) << 4;
            ah[f] = *(const v8s*)((const char*)Ah[cur] + ra);
            al[f] = *(const v8s*)((const char*)Al[cur] + ra);
            int rb = (wn * 64 + f * 16 + lm) * 64 + lk * 16;
            rb ^= ((rb >> 6) & 7) << 4;
            bh[f] = *(const v8s*)((const char*)Wh[cur] + rb);
            bl[f] = *(const v8s*)((const char*)Wl[cur] + rb);
        }
#pragma unroll
        for (int fm = 0; fm < 4; ++fm) {
#pragma unroll
            for (int fn = 0; fn < 4; ++fn) {
                acc[fm][fn] = __builtin_amdgcn_mfma_f32_16x16x32_bf16(
                    ah[fm], bh[fn], acc[fm][fn], 0, 0, 0);
                acc[fm][fn] = __builtin_amdgcn_mfma_f32_16x16x32_bf16(
                    ah[fm], bl[fn], acc[fm][fn], 0, 0, 0);
                acc[fm][fn] = __builtin_amdgcn_mfma_f32_16x16x32_bf16(
                    al[fm], bh[fn], acc[fm][fn], 0, 0, 0);
            }
        }
    }

#pragma unroll
    for (int fn = 0; fn < 4; ++fn) {
        int col = col0 + wn * 64 + fn * 16 + lm;
        if (col < GATES) {
            float bias = b1[col] + b2[col];
#pragma unroll
            for (int fm = 0; fm < 4; ++fm) {
                v4f d = acc[fm][fn];
                int rbase = row0 + wm * 64 + fm * 16 + lk * 4;
#pragma unroll
                for (int p = 0; p < 4; ++p)
                    out[(size_t)(rbase + p) * GATES + col] = d[p] + bias;
            }
        }
    }
}

// weight-load macro: 25 scalar loads packed into 7 named float4 (pads zero)
#define LOADW(W0, W1, W2, W3, W4, W5, W6, P)                 \
    W0 = make_float4((P)[0],  (P)[1],  (P)[2],  (P)[3]);     \
    W1 = make_float4((P)[4],  (P)[5],  (P)[6],  (P)[7]);     \
    W2 = make_float4((P)[8],  (P)[9],  (P)[10], (P)[11]);    \
    W3 = make_float4((P)[12], (P)[13], (P)[14], (P)[15]);    \
    W4 = make_float4((P)[16], (P)[17], (P)[18], (P)[19]);    \
    W5 = make_float4((P)[20], (P)[21], (P)[22], (P)[23]);    \
    W6 = make_float4((P)[24], 0.f, 0.f, 0.f);

#define DOT4(S, W, H)                                        \
    S += (W).x * (H).x; S += (W).y * (H).y;                  \
    S += (W).z * (H).z; S += (W).w * (H).w;

// ---------------------------------------------------------------------------
// Recurrent scan v8: round-12 structure, weights in 28 INDIVIDUALLY-NAMED
// float4 variables. Rule #20: arrays (even constant-indexed, even with asm
// keep-alives -- rounds 13-15, VGPR stuck at 80-88) get lowered to scratch
// and re-fetched from L1/L2 every step (~200 KB/block/step = the measured
// 2520 cyc/step wall). Named scalars cannot be array-lowered; SROA keeps
// them in SSA and they allocate as VGPRs (~175 live). Round 6's 1-D w[100]
// promoting to VGPR=156 is the existence proof.
// ---------------------------------------------------------------------------
template <bool WRITE_ALL>
__global__ __launch_bounds__(448) void lstm_recur(
    const float* __restrict__ xg,    // [B, T, 400]
    const float* __restrict__ w_hh,  // [400, 100]
    const int*   __restrict__ lengths,
    float* __restrict__ hs)          // [B, T, 100]
{
    const int b   = blockIdx.x;
    const int tid = threadIdx.x;
    const bool active = (tid < 400);
    const int j   = tid >> 2;
    const int jc  = (j < HID) ? j : (HID - 1);   // clamp: loads unconditional
    const int gt  = tid & 3;

    __shared__ float xg_s[32 * GATES];
    __shared__ float h_s[2][112];
    __shared__ float h_hist[32 * HID];

    float4 w00, w01, w02, w03, w04, w05, w06;   // gate 0 (i)
    float4 w10, w11, w12, w13, w14, w15, w16;   // gate 1 (f)
    float4 w20, w21, w22, w23, w24, w25, w26;   // gate 2 (g)
    float4 w30, w31, w32, w33, w34, w35, w36;   // gate 3 (o)
    {
        const float* p0 = w_hh + (size_t)(0 * HID + jc) * HID + gt * 25;
        const float* p1 = w_hh + (size_t)(1 * HID + jc) * HID + gt * 25;
        const float* p2 = w_hh + (size_t)(2 * HID + jc) * HID + gt * 25;
        const float* p3 = w_hh + (size_t)(3 * HID + jc) * HID + gt * 25;
        LOADW(w00, w01, w02, w03, w04, w05, w06, p0)
        LOADW(w10, w11, w12, w13, w14, w15, w16, p1)
        LOADW(w20, w21, w22, w23, w24, w25, w26, p2)
        LOADW(w30, w31, w32, w33, w34, w35, w36, p3)
    }

    for (int i = tid; i < 224; i += 448) ((float*)h_s)[i] = 0.f;

    float c_reg = 0.f, h_reg = 0.f;
    const int len = lengths[b];
    const float* xgb = xg + (size_t)b * T_STEPS * GATES;
    float*       hsb = hs + (size_t)b * T_STEPS * HID;

    const bool is0 = (gt == 0), is1 = (gt == 1), is2 = (gt == 2);
    const int  hoff = gt * 28;
    const int  seg  = (jc / 25) * 28 + (jc % 25);
    const int  xcol = gt * HID + jc;

    for (int t = 0; t < T_STEPS; ++t) {
        if ((t & 31) == 0) {
            if (WRITE_ALL && t > 0) {
                const float4* s = (const float4*)h_hist;
                float4*       d = (float4*)(hsb + (size_t)(t - 32) * HID);
                for (int i = tid; i < 800; i += 448) d[i] = s[i];
            }
            const float4* src = (const float4*)(xgb + (size_t)t * GATES);
            float4*       dst = (float4*)xg_s;
            for (int i = tid; i < 3200; i += 448) dst[i] = src[i];
            __syncthreads();
        }

        float s0 = 0.f, s1 = 0.f, s2 = 0.f, s3 = 0.f;
        {
            const float4* hb = (const float4*)(h_s[t & 1] + hoff);
            float4 ha = hb[0], hb1 = hb[1], hc = hb[2], hd = hb[3],
                   he = hb[4], hf = hb[5], hg = hb[6];
            DOT4(s0, w00, ha) DOT4(s0, w01, hb1) DOT4(s0, w02, hc)
            DOT4(s0, w03, hd) DOT4(s0, w04, he)  DOT4(s0, w05, hf)
            DOT4(s0, w06, hg)
            DOT4(s1, w10, ha) DOT4(s1, w11, hb1) DOT4(s1, w12, hc)
            DOT4(s1, w13, hd) DOT4(s1, w14, he)  DOT4(s1, w15, hf)
            DOT4(s1, w16, hg)
            DOT4(s2, w20, ha) DOT4(s2, w21, hb1) DOT4(s2, w22, hc)
            DOT4(s2, w23, hd) DOT4(s2, w24, he)  DOT4(s2, w25, hf)
            DOT4(s2, w26, hg)
            DOT4(s3, w30, ha) DOT4(s3, w31, hb1) DOT4(s3, w32, hc)
            DOT4(s3, w33, hd) DOT4(s3, w34, he)  DOT4(s3, w35, hf)
            DOT4(s3, w36, hg)
        }
        s0 += __shfl_xor(s0, 1); s0 += __shfl_xor(s0, 2);
        s1 += __shfl_xor(s1, 1); s1 += __shfl_xor(s1, 2);
        s2 += __shfl_xor(s2, 1); s2 += __shfl_xor(s2, 2);
        s3 += __shfl_xor(s3, 1); s3 += __shfl_xor(s3, 2);

        float sg  = is0 ? s0 : is1 ? s1 : is2 ? s2 : s3;
        float pre = sg + xg_s[(t & 31) * GATES + xcol];

        float p0 = is2 ? tanh_f(pre) : sigm_f(pre);
        float p1 = __shfl_xor(p0, 1);
        float p2 = __shfl_xor(p0, 2);
        float p3 = __shfl_xor(p1, 2);
        float iv = is0 ? p0 : is1 ? p1 : is2 ? p2 : p3;
        float fv = is0 ? p1 : is1 ? p0 : is2 ? p3 : p2;
        float gv = is0 ? p2 : is1 ? p3 : is2 ? p0 : p1;
        float ov = is0 ? p3 : is1 ? p2 : is2 ? p1 : p0;

        float c_new = fv * c_reg + iv * gv;
        float h_new = ov * tanh_f(c_new);
        bool  m     = (t < len);
        c_reg = m ? c_new : c_reg;
        h_reg = m ? h_new : h_reg;

        if (active && gt == 0) {
            h_s[(t & 1) ^ 1][seg] = h_reg;
            if (WRITE_ALL) h_hist[(t & 31) * HID + j] = h_reg;
        }
        __syncthreads();
    }

    if (WRITE_ALL) {
        const float4* s = (const float4*)h_hist;
        float4*       d = (float4*)(hsb + (size_t)(T_STEPS - 32) * HID);
        for (int i = tid; i < 800; i += 448) d[i] = s[i];
    } else {
        if (active && gt == 0)
            hsb[(size_t)(T_STEPS - 1) * HID + j] = h_reg;
    }
}

// ---------------------------------------------------------------------------
// Final linear head
// ---------------------------------------------------------------------------
__global__ __launch_bounds__(64) void fc_kernel(
    const float* __restrict__ hs, const float* __restrict__ w_fc,
    const float* __restrict__ b_fc, float* __restrict__ out)
{
    int tid = blockIdx.x * 64 + threadIdx.x;
    if (tid >= BATCH * 3) return;
    int b = tid / 3, o = tid % 3;
    const float* h = hs + ((size_t)b * T_STEPS + (T_STEPS - 1)) * HID;
    float acc = b_fc[o];
    for (int j = 0; j < HID; ++j) acc += h[j] * w_fc[o * HID + j];
    out[b * 3 + o] = acc;
}

extern "C" void kernel_launch(void* const* d_in, const int* in_sizes, int n_in,
                              void* d_out, int out_size, void* d_ws, size_t ws_size,
                              hipStream_t stream)
{
    const int*   x       = (const int*)  d_in[0];
    const int*   lengths = (const int*)  d_in[1];
    const float* emb     = (const float*)d_in[2];
    const float* w_ih0   = (const float*)d_in[3];
    const float* w_hh0   = (const float*)d_in[4];
    const float* b_ih0   = (const float*)d_in[5];
    const float* b_hh0   = (const float*)d_in[6];
    const float* w_ih1   = (const float*)d_in[7];
    const float* w_hh1   = (const float*)d_in[8];
    const float* b_ih1   = (const float*)d_in[9];
    const float* b_hh1   = (const float*)d_in[10];
    const float* w_ih2   = (const float*)d_in[11];
    const float* w_hh2   = (const float*)d_in[12];
    const float* b_ih2   = (const float*)d_in[13];
    const float* b_hh2   = (const float*)d_in[14];
    const float* w_fc    = (const float*)d_in[15];
    const float* b_fc    = (const float*)d_in[16];
    float* out = (float*)d_out;

    float* xg = (float*)d_ws;                  // [BT, 400]  ~210 MB
    float* hs = xg + (size_t)BT * GATES;       // [BT, 100]  ~52 MB

    const int nblk = (BT / 128) * 4;   // 4096, XCD-swizzled inside kernel

    // Layer 0: embedding gather fused into staging, K=300 (pad 320)
    xg_gemm<300, 10, true><<<nblk, 256, 0, stream>>>(emb, x, w_ih0, b_ih0, b_hh0, xg);
    lstm_recur<true><<<BATCH, 448, 0, stream>>>(xg, w_hh0, lengths, hs);

    // Layer 1: K=100 (pad 128)
    xg_gemm<100, 4, false><<<nblk, 256, 0, stream>>>(hs, nullptr, w_ih1, b_ih1, b_hh1, xg);
    lstm_recur<true><<<BATCH, 448, 0, stream>>>(xg, w_hh1, lengths, hs);

    // Layer 2
    xg_gemm<100, 4, false><<<nblk, 256, 0, stream>>>(hs, nullptr, w_ih2, b_ih2, b_hh2, xg);
    lstm_recur<false><<<BATCH, 448, 0, stream>>>(xg, w_hh2, lengths, hs);

    // Head
    fc_kernel<<<(BATCH * 3 + 63) / 64, 64, 0, stream>>>(hs, w_fc, b_fc, out);
}